// Round 1
// baseline (440.030 us; speedup 1.0000x reference)
//
#include <hip/hip_runtime.h>

#define DD 256
#define KK 8192
#define HW 1024
#define NROWS 16384
#define NELEM 4194304
#define MT 32
#define MARGIN 6e-4f
#define WCAP 512
#define NSLICE 4   // code slices; bid = rt*4+cs -> XCD x serves only cs = x&3

typedef __attribute__((ext_vector_type(8))) short short8;
typedef __attribute__((ext_vector_type(4))) float f32x4;
typedef unsigned short ushort;
typedef unsigned int uint;
typedef unsigned long long u64;

// ---- exact replication of numpy pairwise_sum (n=256) over squares ----
__device__ __forceinline__ float np_pw128_sq(const float* p) {
  float r[8];
#pragma unroll
  for (int j = 0; j < 8; ++j) r[j] = __fmul_rn(p[j], p[j]);
  for (int i = 8; i < 128; i += 8) {
#pragma unroll
    for (int j = 0; j < 8; ++j)
      r[j] = __fadd_rn(r[j], __fmul_rn(p[i + j], p[i + j]));
  }
  return __fadd_rn(__fadd_rn(__fadd_rn(r[0], r[1]), __fadd_rn(r[2], r[3])),
                   __fadd_rn(__fadd_rn(r[4], r[5]), __fadd_rn(r[6], r[7])));
}

__device__ __forceinline__ ushort f2bf(float x) {   // RNE float->bf16 bits
  uint u = __float_as_uint(x);
  u += 0x7FFF + ((u >> 16) & 1);
  return (ushort)(u >> 16);
}

// ======== merged prep: transpose | norms | arow | cbB fragments ========
__global__ __launch_bounds__(256) void vq_prep(const float* __restrict__ z,
                                               const float* __restrict__ cb,
                                               float* __restrict__ cbT,
                                               float* __restrict__ Bk,
                                               float* __restrict__ Arow,
                                               ushort* __restrict__ cbB) {
  __shared__ float tile[64][65];
  const int b = blockIdx.x, t = threadIdx.x;
  if (b < 512) {               // cbT[d][k] = cb[k][d]
    int k0 = (b & 127) * 64, d0 = (b >> 7) * 64;
    for (int li = t; li < 64 * 64; li += 256) {
      int kk = li >> 6, dd = li & 63;
      tile[kk][dd] = cb[(size_t)(k0 + kk) * DD + d0 + dd];
    }
    __syncthreads();
    for (int li = t; li < 64 * 64; li += 256) {
      int dd = li >> 6, kk = li & 63;
      cbT[(size_t)(d0 + dd) * KK + k0 + kk] = tile[kk][dd];
    }
  } else if (b < 544) {        // ||e_k||^2, numpy-exact
    int k = (b - 512) * 256 + t;
    const float* p = cb + (size_t)k * DD;
    Bk[k] = __fadd_rn(np_pw128_sq(p), np_pw128_sq(p + 128));
  } else if (b < 608) {        // ||z_n||^2, numpy-exact (strided)
    int n = (b - 544) * 256 + t;
    int bimg = n >> 10, hw = n & 1023;
    const float* zp = z + (size_t)bimg * DD * HW + hw;
    float h[2];
#pragma unroll
    for (int half = 0; half < 2; ++half) {
      float r[8];
#pragma unroll
      for (int j = 0; j < 8; ++j) {
        float v = zp[(size_t)(half * 128 + j) * HW];
        r[j] = __fmul_rn(v, v);
      }
      for (int i = 8; i < 128; i += 8) {
#pragma unroll
        for (int j = 0; j < 8; ++j) {
          float v = zp[(size_t)(half * 128 + i + j) * HW];
          r[j] = __fadd_rn(r[j], __fmul_rn(v, v));
        }
      }
      h[half] = __fadd_rn(__fadd_rn(__fadd_rn(r[0], r[1]), __fadd_rn(r[2], r[3])),
                          __fadd_rn(__fadd_rn(r[4], r[5]), __fadd_rn(r[6], r[7])));
    }
    Arow[n] = __fadd_rn(h[0], h[1]);
  } else {                     // cbB fragments (layout verified r7/r8/r9)
    int tid = (b - 608) * 256 + t;
    int g = tid >> 9, s = (tid >> 6) & 7, lane = tid & 63;
    int code = g * 16 + (lane & 15);
    int dbase = s * 32 + (lane >> 4) * 8;
    const float* p = cb + (size_t)code * DD + dbase;
    ushort bb[8];
#pragma unroll
    for (int j = 0; j < 8; ++j) bb[j] = f2bf(p[j]);
    uint4 pk;
    pk.x = bb[0] | ((uint)bb[1] << 16);
    pk.y = bb[2] | ((uint)bb[3] << 16);
    pk.z = bb[4] | ((uint)bb[5] << 16);
    pk.w = bb[6] | ((uint)bb[7] << 16);
    *(uint4*)(cbB + (size_t)tid * 8) = pk;
  }
}

// ======== screen: 512 row-tiles x 4 code-slices; cbB slice L2-resident ======
// bid = rt*4+cs: round-robin XCD assignment gives XCD x only cs = x&3, so
// each XCD's 4 MB L2 holds a 1.05 MB cbB slice permanently. Per-tile minima
// go to global gminG (disjoint writes, no atomics). Inner loop identical to
// the verified fused screen (same MFMA/fmin sequence -> bit-identical gmin).
__global__ __launch_bounds__(256) void vq_screen(
    const float* __restrict__ z, const ushort* __restrict__ cbB,
    const float* __restrict__ Bk, float* __restrict__ gminG) {
  __shared__ float zt[MT][DD + 1];
  const int bid = blockIdx.x;
  const int rt = bid >> 2, cs = bid & 3;
  const int t = threadIdx.x;
  const int n0 = rt * MT;
  const int bimg = n0 >> 10, hw0 = n0 & 1023;
  const float* zb = z + (size_t)bimg * DD * HW + hw0;

  for (int li = t; li < MT * DD; li += 256) {
    int d = li >> 5, r = li & 31;
    zt[r][d] = zb[d * HW + r];
  }
  __syncthreads();

  const int w = t >> 6, lane = t & 63;
  const int quad = lane >> 4, n16 = lane & 15;

  // A-fragments for BOTH 16-row groups (m89-verified layout), in registers.
  short8 aF[2][8];
#pragma unroll
  for (int rg = 0; rg < 2; ++rg)
#pragma unroll
    for (int s = 0; s < 8; ++s) {
      const float* zp = &zt[rg * 16 + n16][s * 32 + quad * 8];
      short8 v;
#pragma unroll
      for (int j = 0; j < 8; ++j) v[j] = (short)f2bf(zp[j]);
      aF[rg][s] = v;
    }

  // ---- wave owns 512 codes = 32 groups of 16; no barriers ----
  const int g0 = cs * 128 + w * 32;
  float m40[4] = {3.4e38f, 3.4e38f, 3.4e38f, 3.4e38f};
  float m41[4] = {3.4e38f, 3.4e38f, 3.4e38f, 3.4e38f};

  short8 b0[8], b1[8];
  {
    const ushort* bp = cbB + (size_t)g0 * 4096 + lane * 8;
#pragma unroll
    for (int s = 0; s < 8; ++s) b0[s] = *(const short8*)(bp + s * 512);
  }

  for (int gp = 0; gp < 16; ++gp) {     // hand-pipelined pairs: b0/b1 ping-pong
    const int gg = g0 + gp * 2;
    {   // prefetch odd group while even computes
      const ushort* bp = cbB + (size_t)(gg + 1) * 4096 + lane * 8;
#pragma unroll
      for (int s = 0; s < 8; ++s) b1[s] = *(const short8*)(bp + s * 512);
    }
    {   // even group
      f32x4 a0 = {0.f, 0.f, 0.f, 0.f}, a1 = {0.f, 0.f, 0.f, 0.f};
#pragma unroll
      for (int s = 0; s < 8; ++s) {
        a0 = __builtin_amdgcn_mfma_f32_16x16x32_bf16(aF[0][s], b0[s], a0, 0, 0, 0);
        a1 = __builtin_amdgcn_mfma_f32_16x16x32_bf16(aF[1][s], b0[s], a1, 0, 0, 0);
      }
      const float Bs = Bk[gg * 16 + n16];
#pragma unroll
      for (int reg = 0; reg < 4; ++reg) {
        m40[reg] = fminf(m40[reg], fmaf(-2.f, a0[reg], Bs));
        m41[reg] = fminf(m41[reg], fmaf(-2.f, a1[reg], Bs));
      }
    }
    if (gp < 15) {   // prefetch next even group while odd computes
      const ushort* bp = cbB + (size_t)(gg + 2) * 4096 + lane * 8;
#pragma unroll
      for (int s = 0; s < 8; ++s) b0[s] = *(const short8*)(bp + s * 512);
    }
    {   // odd group
      f32x4 a0 = {0.f, 0.f, 0.f, 0.f}, a1 = {0.f, 0.f, 0.f, 0.f};
#pragma unroll
      for (int s = 0; s < 8; ++s) {
        a0 = __builtin_amdgcn_mfma_f32_16x16x32_bf16(aF[0][s], b1[s], a0, 0, 0, 0);
        a1 = __builtin_amdgcn_mfma_f32_16x16x32_bf16(aF[1][s], b1[s], a1, 0, 0, 0);
      }
      const float Bs = Bk[(gg + 1) * 16 + n16];
#pragma unroll
      for (int reg = 0; reg < 4; ++reg) {
        m40[reg] = fminf(m40[reg], fmaf(-2.f, a0[reg], Bs));
        m41[reg] = fminf(m41[reg], fmaf(-2.f, a1[reg], Bs));
      }
    }
    if (gp & 1) {    // 4 groups (64 codes) done: reduce over 16 code-lanes
#pragma unroll
      for (int off = 1; off < 16; off <<= 1)
#pragma unroll
        for (int reg = 0; reg < 4; ++reg) {
          m40[reg] = fminf(m40[reg], __shfl_xor(m40[reg], off));
          m41[reg] = fminf(m41[reg], __shfl_xor(m41[reg], off));
        }
      if (n16 == 0) {
        const int tile = (gg + 1) >> 2;   // wave-disjoint tiles: plain stores
#pragma unroll
        for (int reg = 0; reg < 4; ++reg) {
          gminG[(size_t)(n0 + quad * 4 + reg) * 128 + tile] = m40[reg];
          gminG[(size_t)(n0 + 16 + quad * 4 + reg) * 128 + tile] = m41[reg];
        }
      }
#pragma unroll
      for (int reg = 0; reg < 4; ++reg) { m40[reg] = 3.4e38f; m41[reg] = 3.4e38f; }
    }
  }
}

// ======== rerank + epilogue: threshold | worklist | exact | outputs ========
__global__ __launch_bounds__(256) void vq_rerank(
    const float* __restrict__ z, const float* __restrict__ cbT,
    const float* __restrict__ cb, const float* __restrict__ Bk,
    const float* __restrict__ Arow, const float* __restrict__ gminG,
    float* __restrict__ out, int* __restrict__ hist,
    float* __restrict__ loss_acc, u64* __restrict__ rowBest) {
  __shared__ float zt[MT][DD + 1];    // 32.9 KB, staged once, lives to the end
  __shared__ float gmin[MT][129];     // 16.5 KB (pad: kills 32-way col scan)
  __shared__ float thr[MT];
  __shared__ float ArS[MT];
  __shared__ int wl[WCAP];
  __shared__ int wcnt;
  __shared__ int kwin[MT];
  __shared__ float lred[4];

  const int t = threadIdx.x;
  const int n0 = blockIdx.x * MT;
  const int bimg = n0 >> 10, hw0 = n0 & 1023;
  const float* zb = z + (size_t)bimg * DD * HW + hw0;

  if (t == 0) wcnt = 0;
  if (t < MT) ArS[t] = Arow[n0 + t];
  for (int li = t; li < MT * DD; li += 256) {
    int d = li >> 5, r = li & 31;
    zt[r][d] = zb[d * HW + r];
  }
  for (int li = t; li < MT * 128; li += 256)       // coalesced gminG stage
    gmin[li >> 7][li & 127] = gminG[(size_t)n0 * 128 + li];
  __syncthreads();

  const int w = t >> 6, lane = t & 63;

  // ---- per-row global threshold ----
  if (t < MT) {
    float mn = gmin[t][0];
    for (int c = 1; c < 128; ++c) mn = fminf(mn, gmin[t][c]);
    thr[t] = mn + MARGIN;
  }
  __syncthreads();

  // ---- worklist build ----
  for (int idx = t; idx < MT * 128; idx += 256) {
    int r = idx >> 7, g = idx & 127;
    if (gmin[r][g] <= thr[r]) {
      int pos = atomicAdd(&wcnt, 1);
      if (pos < WCAP) {
        wl[pos] = (r << 16) | g;
      } else {   // overflow fallback (never in practice): scalar exact scan
        float bd = 3.4e38f;
        int bi = 0;
        for (int c = 0; c < 64; ++c) {
          int code = g * 64 + c;
          const float* ep = cb + (size_t)code * DD;
          float dot = 0.f;
          for (int d = 0; d < DD; ++d) dot = fmaf(zt[r][d], ep[d], dot);
          float dist = __fsub_rn(__fadd_rn(ArS[r], Bk[code]),
                                 __fmul_rn(2.f, dot));
          if (dist < bd) { bd = dist; bi = code; }
        }
        atomicMin(&rowBest[n0 + r],
                  ((u64)__float_as_uint(bd) << 32) | (unsigned)bi);
      }
    }
  }
  __syncthreads();

  // ---- exact re-rank: one wave per flagged (row, 64-code group) ----
  // batched strided loads (r9) + ascending-d fmaf chain (numpy-exact order)
  const int cnt = min(wcnt, WCAP);
  for (int e = w; e < cnt; e += 4) {
    const int ent = wl[e];
    const int r = ent >> 16, g = ent & 0xFFFF;
    const int code = g * 64 + lane;
    const float* cp = cbT + code;
    float dot = 0.f;
#pragma unroll
    for (int d0 = 0; d0 < DD; d0 += 64) {
      float v[64];
#pragma unroll
      for (int j = 0; j < 64; ++j) v[j] = cp[(size_t)(d0 + j) * KK];
#pragma unroll
      for (int j = 0; j < 64; ++j) dot = fmaf(zt[r][d0 + j], v[j], dot);
    }
    float bd = __fsub_rn(__fadd_rn(ArS[r], Bk[code]), __fmul_rn(2.f, dot));
    int bi = code;
#pragma unroll
    for (int off = 1; off < 64; off <<= 1) {   // lex (dist, idx) min
      float pd = __shfl_xor(bd, off);
      int pi = __shfl_xor(bi, off);
      if (pd < bd || (pd == bd && pi < bi)) { bd = pd; bi = pi; }
    }
    if (lane == 0)
      atomicMin(&rowBest[n0 + r],
                ((u64)__float_as_uint(bd) << 32) | (unsigned)bi);
  }
  __syncthreads();

  // ---- epilogue: indices + hist + z_q_st + loss (zt resident) ----
  if (t < MT) {
    u64 key = atomicMin(&rowBest[n0 + t], 0xFFFFFFFFFFFFFFFFull);  // read
    int bi = (int)(key & 0xFFFFFFFFull);
    kwin[t] = bi;
    atomicAdd(&hist[bi], 1);
    out[(size_t)NELEM + 1 + n0 + t] = (float)bi;
  }
  __syncthreads();

  float lsum = 0.f;
  for (int it = 0; it < MT * DD / 256; ++it) {
    int li = it * 256 + t;
    int d = li >> 5, r = li & 31;
    float ze = zt[r][d];
    float zq = cb[(size_t)kwin[r] * DD + d];
    float diff = __fsub_rn(zq, ze);
    float st = __fadd_rn(ze, diff);        // z_e + (z_q - z_e)
    out[(size_t)(bimg * DD + d) * HW + hw0 + r] = st;
    lsum = fmaf(diff, diff, lsum);
  }
#pragma unroll
  for (int off = 32; off > 0; off >>= 1) lsum += __shfl_down(lsum, off);
  if (lane == 0) lred[w] = lsum;
  __syncthreads();
  if (t == 0)
    atomicAdd(loss_acc, ((lred[0] + lred[1]) + (lred[2] + lred[3])));
}

// ---------------- finalize: vq_loss + perplexity ----------------
__global__ __launch_bounds__(256) void vq_final(const int* __restrict__ hist,
                                                const float* __restrict__ loss,
                                                float* __restrict__ out) {
  __shared__ float sred[256];
  int t = threadIdx.x;
  float s = 0.f;
  for (int k = t; k < KK; k += 256) {
    float p = (float)hist[k] * (1.f / 16384.f);
    s += p * logf(p + 1e-10f);
  }
  sred[t] = s;
  __syncthreads();
  for (int off = 128; off > 0; off >>= 1) {
    if (t < off) sred[t] += sred[t + off];
    __syncthreads();
  }
  if (t == 0) {
    float L = loss[0] / (float)NELEM;
    out[NELEM] = 1.25f * L;
    out[(size_t)NELEM + 1 + NROWS] = expf(-sred[0]);
  }
}

extern "C" void kernel_launch(void* const* d_in, const int* in_sizes, int n_in,
                              void* d_out, int out_size, void* d_ws, size_t ws_size,
                              hipStream_t stream) {
  const float* z = (const float*)d_in[0];   // (16,256,32,32) fp32
  const float* cb = (const float*)d_in[1];  // (8192,256) fp32
  float* out = (float*)d_out;               // fp32: [z_q_st | loss | idx | perp]

  float* wsf = (float*)d_ws;
  int* hist = (int*)d_ws;                          // 8192 ints
  float* loss = wsf + 8192;                        // 1 (+pad)
  float* Bk = wsf + 8448;                          // 8192
  float* Arow = wsf + 16640;                       // 16384
  u64* rowBest = (u64*)(wsf + 33024);              // 16384 u64 (128 KB)
  ushort* cbB = (ushort*)(wsf + 65792);            // 2.10M ushorts (4.2 MB)
  float* cbT = wsf + 65792 + 1048576;              // 2M floats (8 MB)
  float* gminG = wsf + 65792 + 1048576 + 2097152;  // 2.10M floats (8.4 MB)

  hipMemsetAsync(d_ws, 0, 8448 * sizeof(float), stream);
  hipMemsetAsync(rowBest, 0xFF, NROWS * sizeof(u64), stream);
  vq_prep<<<1632, 256, 0, stream>>>(z, cb, cbT, Bk, Arow, cbB);
  vq_screen<<<(NROWS / MT) * NSLICE, 256, 0, stream>>>(z, cbB, Bk, gminG);
  vq_rerank<<<NROWS / MT, 256, 0, stream>>>(z, cbT, cb, Bk, Arow, gminG, out,
                                            hist, loss, rowBest);
  vq_final<<<1, 256, 0, stream>>>(hist, loss, out);
}

// Round 2
// 242.573 us; speedup vs baseline: 1.8140x; 1.8140x over previous
//
#include <hip/hip_runtime.h>

#define DD 256
#define KK 8192
#define HW 1024
#define NROWS 16384
#define NELEM 4194304
#define MT 32
#define MARGIN 6e-4f
#define WCAP 512
#define NT 256          // 8192 codes / 32-code tiles

typedef __attribute__((ext_vector_type(8))) short short8;
typedef __attribute__((ext_vector_type(4))) float f32x4;
typedef unsigned short ushort;
typedef unsigned int uint;
typedef unsigned long long u64;

// ---- exact replication of numpy pairwise_sum (n=256) over squares ----
__device__ __forceinline__ float np_pw128_sq(const float* p) {
  float r[8];
#pragma unroll
  for (int j = 0; j < 8; ++j) r[j] = __fmul_rn(p[j], p[j]);
  for (int i = 8; i < 128; i += 8) {
#pragma unroll
    for (int j = 0; j < 8; ++j)
      r[j] = __fadd_rn(r[j], __fmul_rn(p[i + j], p[i + j]));
  }
  return __fadd_rn(__fadd_rn(__fadd_rn(r[0], r[1]), __fadd_rn(r[2], r[3])),
                   __fadd_rn(__fadd_rn(r[4], r[5]), __fadd_rn(r[6], r[7])));
}

__device__ __forceinline__ ushort f2bf(float x) {   // RNE float->bf16 bits
  uint u = __float_as_uint(x);
  u += 0x7FFF + ((u >> 16) & 1);
  return (ushort)(u >> 16);
}

__device__ __forceinline__ void emit8(ushort* __restrict__ zB, int g, int n16,
                                      int d0, const float* vv) {
  int s = d0 >> 5, q = (d0 >> 3) & 3;
  uint4 pk;
  pk.x = f2bf(vv[0]) | ((uint)f2bf(vv[1]) << 16);
  pk.y = f2bf(vv[2]) | ((uint)f2bf(vv[3]) << 16);
  pk.z = f2bf(vv[4]) | ((uint)f2bf(vv[5]) << 16);
  pk.w = f2bf(vv[6]) | ((uint)f2bf(vv[7]) << 16);
  *(uint4*)(zB + ((size_t)g * 512 + s * 64 + q * 16 + n16) * 8) = pk;
}

// running top-2 (min, argmin, min2) helpers for the screen
struct Top2 { float m1, m2; int i1; };

__device__ __forceinline__ void top2_upd(Top2& s, const f32x4 a,
                                         const f32x4 Bs, int ibase) {
  float d0 = fmaf(-2.f, a[0], Bs[0]);
  float d1 = fmaf(-2.f, a[1], Bs[1]);
  float d2 = fmaf(-2.f, a[2], Bs[2]);
  float d3 = fmaf(-2.f, a[3], Bs[3]);
  float lo01 = fminf(d0, d1), hi01 = fmaxf(d0, d1);
  int io01 = d1 < d0 ? ibase + 1 : ibase;
  float lo23 = fminf(d2, d3), hi23 = fmaxf(d2, d3);
  int io23 = d3 < d2 ? ibase + 3 : ibase + 2;
  float n1 = fminf(lo01, lo23);
  int ni = lo23 < lo01 ? io23 : io01;
  float n2 = fminf(fmaxf(lo01, lo23), fminf(hi01, hi23));
  s.m2 = fminf(fmaxf(s.m1, n1), fminf(s.m2, n2));   // uses OLD m1
  s.i1 = n1 < s.m1 ? ni : s.i1;
  s.m1 = fminf(s.m1, n1);
}

__device__ __forceinline__ void top2_bfly(Top2& s, int off) {
  float om1 = __shfl_xor(s.m1, off);
  int oi1 = __shfl_xor(s.i1, off);
  float om2 = __shfl_xor(s.m2, off);
  s.m2 = fminf(fmaxf(s.m1, om1), fminf(s.m2, om2));
  s.i1 = om1 < s.m1 ? oi1 : s.i1;   // ties keep own; covered by m2<=thr path
  s.m1 = fminf(s.m1, om1);
}

__device__ __forceinline__ uint pack_m2(float m2, int i1) {
  // bf16 rounded toward -inf (conservative: never hides a full-scan), idx in low bits
  uint u = __float_as_uint(m2);
  uint hi = u & 0xFFFF0000u;
  if ((u & 0x80000000u) && (u & 0xFFFFu)) hi += 0x10000u;
  return hi | (uint)i1;
}

// ======== prep: Bk | Arow+zB fused | cbB fragments (cbT dropped) ========
__global__ __launch_bounds__(256) void vq_prep(const float* __restrict__ z,
                                               const float* __restrict__ cb,
                                               float* __restrict__ Bk,
                                               float* __restrict__ Arow,
                                               ushort* __restrict__ cbB,
                                               ushort* __restrict__ zB) {
  const int b = blockIdx.x, t = threadIdx.x;
  if (b < 32) {                // ||e_k||^2, numpy-exact
    int k = b * 256 + t;
    const float* p = cb + (size_t)k * DD;
    Bk[k] = __fadd_rn(np_pw128_sq(p), np_pw128_sq(p + 128));
  } else if (b < 160) {        // ||z_n||^2 half (numpy-exact) + zB fragments
    int tid = (b - 32) * 256 + t;        // 2 threads per row (d-halves)
    int n = tid >> 1, half = tid & 1;
    int bimg = n >> 10, hw = n & 1023;
    const float* zp = z + (size_t)bimg * DD * HW + hw;
    const int g = n >> 4, n16 = n & 15;
    const int dbase = half * 128;
    float r[8], vv[8];
#pragma unroll
    for (int j = 0; j < 8; ++j) {
      vv[j] = zp[(size_t)(dbase + j) * HW];
      r[j] = __fmul_rn(vv[j], vv[j]);
    }
    emit8(zB, g, n16, dbase, vv);
    for (int i = 8; i < 128; i += 8) {
      const int dd = dbase + i;
#pragma unroll
      for (int j = 0; j < 8; ++j) {
        vv[j] = zp[(size_t)(dd + j) * HW];
        r[j] = __fadd_rn(r[j], __fmul_rn(vv[j], vv[j]));
      }
      emit8(zB, g, n16, dd, vv);
    }
    float h = __fadd_rn(__fadd_rn(__fadd_rn(r[0], r[1]), __fadd_rn(r[2], r[3])),
                        __fadd_rn(__fadd_rn(r[4], r[5]), __fadd_rn(r[6], r[7])));
    float ho = __shfl_xor(h, 1);   // partner half (adjacent lane)
    if (half == 0) Arow[n] = __fadd_rn(h, ho);   // h[0] + h[1], order preserved
  } else {                     // cbB fragments (layout verified r7/r8/r9)
    int tid = (b - 160) * 256 + t;
    int g = tid >> 9, s = (tid >> 6) & 7, lane = tid & 63;
    int code = g * 16 + (lane & 15);
    int dbase = s * 32 + (lane >> 4) * 8;
    const float* p = cb + (size_t)code * DD + dbase;
    ushort bb[8];
#pragma unroll
    for (int j = 0; j < 8; ++j) bb[j] = f2bf(p[j]);
    uint4 pk;
    pk.x = bb[0] | ((uint)bb[1] << 16);
    pk.y = bb[2] | ((uint)bb[3] << 16);
    pk.z = bb[4] | ((uint)bb[5] << 16);
    pk.w = bb[6] | ((uint)bb[7] << 16);
    *(uint4*)(cbB + (size_t)tid * 8) = pk;
  }
}

// ======== screen: swapped-operand MFMA, per-tile32 (min, argmin, min2) ======
// mfma(codeFrag, zFrag): A/B frag lane-maps are identical (row|col = lane&15,
// k = (lane>>4)*8+j), so cbB serves as A and zB as B unchanged; C layout:
// code = quad*4+reg, z-row = lane&15. Per-(row,code) dots bit-identical to the
// verified kernel. Each lane tracks running top-2 for ITS row over ITS codes
// in-register (no shuffles); one 2-stage butterfly per 32-code tile merges
// quads. tA/tB layout [tile][row]: 128B-coalesced stores AND loads.
__global__ __launch_bounds__(256) void vq_screen(
    const ushort* __restrict__ zB, const ushort* __restrict__ cbB,
    const float* __restrict__ Bk, float* __restrict__ tA,
    uint* __restrict__ tB) {
  const int bid = blockIdx.x;
  const int rt = bid >> 1, cs = bid & 1;   // bid=rt*2+cs -> XCD x gets cs=x&1
  const int t = threadIdx.x;
  const int n0 = rt * MT;
  const int w = t >> 6, lane = t & 63;
  const int quad = lane >> 4, n16 = lane & 15;

  short8 aF[2][8];            // z fragments (B operand), from prep
#pragma unroll
  for (int rg = 0; rg < 2; ++rg) {
    const ushort* zp = zB + (size_t)(rt * 2 + rg) * 4096 + lane * 8;
#pragma unroll
    for (int s = 0; s < 8; ++s) aF[rg][s] = *(const short8*)(zp + s * 512);
  }

  const int gg0 = cs * 256 + w * 64;   // 64 16-code groups = 32 tiles per wave
  Top2 c0 = {3.4e38f, 3.4e38f, 0}, c1 = {3.4e38f, 3.4e38f, 0};

  short8 b0[8], b1[8];
  {
    const ushort* bp = cbB + (size_t)gg0 * 4096 + lane * 8;
#pragma unroll
    for (int s = 0; s < 8; ++s) b0[s] = *(const short8*)(bp + s * 512);
  }

  for (int gp = 0; gp < 32; ++gp) {     // ping-pong pairs; tile = gg pair
    const int gg = gg0 + gp * 2;
    {
      const ushort* bp = cbB + (size_t)(gg + 1) * 4096 + lane * 8;
#pragma unroll
      for (int s = 0; s < 8; ++s) b1[s] = *(const short8*)(bp + s * 512);
    }
    {   // even gg
      f32x4 a0 = {0.f, 0.f, 0.f, 0.f}, a1 = {0.f, 0.f, 0.f, 0.f};
#pragma unroll
      for (int s = 0; s < 8; ++s) {
        a0 = __builtin_amdgcn_mfma_f32_16x16x32_bf16(b0[s], aF[0][s], a0, 0, 0, 0);
        a1 = __builtin_amdgcn_mfma_f32_16x16x32_bf16(b0[s], aF[1][s], a1, 0, 0, 0);
      }
      const f32x4 Bs = *(const f32x4*)(Bk + gg * 16 + quad * 4);
      top2_upd(c0, a0, Bs, quad * 4);
      top2_upd(c1, a1, Bs, quad * 4);
    }
    if (gp < 31) {
      const ushort* bp = cbB + (size_t)(gg + 2) * 4096 + lane * 8;
#pragma unroll
      for (int s = 0; s < 8; ++s) b0[s] = *(const short8*)(bp + s * 512);
    }
    {   // odd gg
      f32x4 a0 = {0.f, 0.f, 0.f, 0.f}, a1 = {0.f, 0.f, 0.f, 0.f};
#pragma unroll
      for (int s = 0; s < 8; ++s) {
        a0 = __builtin_amdgcn_mfma_f32_16x16x32_bf16(b1[s], aF[0][s], a0, 0, 0, 0);
        a1 = __builtin_amdgcn_mfma_f32_16x16x32_bf16(b1[s], aF[1][s], a1, 0, 0, 0);
      }
      const f32x4 Bs = *(const f32x4*)(Bk + (gg + 1) * 16 + quad * 4);
      top2_upd(c0, a0, Bs, 16 + quad * 4);
      top2_upd(c1, a1, Bs, 16 + quad * 4);
    }
    // tile complete: merge quads, store, reset
    top2_bfly(c0, 16); top2_bfly(c0, 32);
    top2_bfly(c1, 16); top2_bfly(c1, 32);
    const size_t tbase = (size_t)(gg >> 1) * NROWS + n0;
    if (quad == 0) {
      tA[tbase + n16] = c0.m1;
      tB[tbase + n16] = pack_m2(c0.m2, c0.i1);
    } else if (quad == 1) {
      tA[tbase + 16 + n16] = c1.m1;
      tB[tbase + 16 + n16] = pack_m2(c1.m2, c1.i1);
    }
    c0.m1 = 3.4e38f; c0.m2 = 3.4e38f; c0.i1 = 0;
    c1.m1 = 3.4e38f; c1.m2 = 3.4e38f; c1.i1 = 0;
  }
}

// ======== rerank: per-code candidates | exact chains | epilogue ========
__global__ __launch_bounds__(256) void vq_rerank(
    const float* __restrict__ z, const float* __restrict__ cb,
    const float* __restrict__ Bk, const float* __restrict__ Arow,
    const float* __restrict__ tA, const uint* __restrict__ tB,
    float* __restrict__ out, int* __restrict__ hist,
    float* __restrict__ loss_acc, u64* __restrict__ rowBest) {
  __shared__ float zt[MT][DD + 1];
  __shared__ float thr[MT];
  __shared__ float ArS[MT];
  __shared__ float partial[4][MT];
  __shared__ int wl[WCAP];
  __shared__ int wcnt;
  __shared__ int kwin[MT];
  __shared__ float lred[4];

  const int t = threadIdx.x;
  const int n0 = blockIdx.x * MT;
  const int bimg = n0 >> 10, hw0 = n0 & 1023;
  const float* zb = z + (size_t)bimg * DD * HW + hw0;

  if (t == 0) wcnt = 0;
  if (t < MT) ArS[t] = Arow[n0 + t];
  for (int li = t; li < MT * DD; li += 256) {
    int d = li >> 5, r = li & 31;
    zt[r][d] = zb[d * HW + r];
  }

  const int w = t >> 6, lane = t & 63;
  const int r = t & 31, j = t >> 5;   // 8 tile-stripes x 32 rows

  // per-row min over 256 tiles ([tile][row] layout: 128B-coalesced)
  float mn = 3.4e38f;
#pragma unroll 4
  for (int k = 0; k < 32; ++k)
    mn = fminf(mn, tA[(size_t)(j * 32 + k) * NROWS + n0 + r]);
  mn = fminf(mn, __shfl_xor(mn, 32));
  if (lane < 32) partial[w][r] = mn;
  __syncthreads();
  if (t < MT)
    thr[t] = fminf(fminf(partial[0][t], partial[1][t]),
                   fminf(partial[2][t], partial[3][t])) + MARGIN;
  __syncthreads();

  auto exact_one = [&](int rr, int code) {   // numpy-exact ascending-d chain
    const float* cp = cb + (size_t)code * DD;
    float dot = 0.f;
#pragma unroll
    for (int d0 = 0; d0 < DD; d0 += 4) {
      float4 v = *(const float4*)(cp + d0);
      dot = fmaf(zt[rr][d0 + 0], v.x, dot);
      dot = fmaf(zt[rr][d0 + 1], v.y, dot);
      dot = fmaf(zt[rr][d0 + 2], v.z, dot);
      dot = fmaf(zt[rr][d0 + 3], v.w, dot);
    }
    float bd = __fsub_rn(__fadd_rn(ArS[rr], Bk[code]), __fmul_rn(2.f, dot));
    atomicMin(&rowBest[n0 + rr],
              ((u64)__float_as_uint(bd) << 32) | (unsigned)code);
  };

  // candidate scan: tile argmin if min<=thr<min2; full 32 codes if min2<=thr
  // (any non-argmin code c in tile has screened(c) >= min2, so this is a
  //  provable superset of {codes with screened <= thr} — same guarantee as
  //  the old tile64 scan, at ~1 code/row instead of 64)
  const float th = thr[r];
  for (int k = 0; k < 32; ++k) {
    const int tile = j * 32 + k;
    const float a = tA[(size_t)tile * NROWS + n0 + r];
    if (a <= th) {
      const uint pk = tB[(size_t)tile * NROWS + n0 + r];
      const float m2f = __uint_as_float(pk & 0xFFFF0000u);
      if (m2f <= th) {               // rare: in-tile near-tie -> full tile
        for (int c = 0; c < 32; ++c) {
          int pos = atomicAdd(&wcnt, 1);
          if (pos < WCAP) wl[pos] = (r << 16) | (tile * 32 + c);
          else exact_one(r, tile * 32 + c);
        }
      } else {
        int pos = atomicAdd(&wcnt, 1);
        if (pos < WCAP) wl[pos] = (r << 16) | (tile * 32 + (int)(pk & 31u));
        else exact_one(r, tile * 32 + (int)(pk & 31u));
      }
    }
  }
  __syncthreads();

  const int cnt = min(wcnt, WCAP);
  for (int e = t; e < cnt; e += 256) {
    const int ent = wl[e];
    exact_one(ent >> 16, ent & 0xFFFF);
  }
  __syncthreads();

  // ---- epilogue: indices + hist + z_q_st + loss (zt resident) ----
  if (t < MT) {
    u64 key = atomicMin(&rowBest[n0 + t], 0xFFFFFFFFFFFFFFFFull);  // read
    int bi = (int)(key & 0xFFFFFFFFull);
    kwin[t] = bi;
    atomicAdd(&hist[bi], 1);
    out[(size_t)NELEM + 1 + n0 + t] = (float)bi;
  }
  __syncthreads();

  float lsum = 0.f;
  for (int it = 0; it < MT * DD / 256; ++it) {
    int li = it * 256 + t;
    int d = li >> 5, rr = li & 31;
    float ze = zt[rr][d];
    float zq = cb[(size_t)kwin[rr] * DD + d];
    float diff = __fsub_rn(zq, ze);
    float st = __fadd_rn(ze, diff);        // z_e + (z_q - z_e)
    out[(size_t)(bimg * DD + d) * HW + hw0 + rr] = st;
    lsum = fmaf(diff, diff, lsum);
  }
#pragma unroll
  for (int off = 32; off > 0; off >>= 1) lsum += __shfl_down(lsum, off);
  if (lane == 0) lred[w] = lsum;
  __syncthreads();
  if (t == 0)
    atomicAdd(loss_acc, ((lred[0] + lred[1]) + (lred[2] + lred[3])));
}

// ---------------- finalize: vq_loss + perplexity ----------------
__global__ __launch_bounds__(256) void vq_final(const int* __restrict__ hist,
                                                const float* __restrict__ loss,
                                                float* __restrict__ out) {
  __shared__ float sred[256];
  int t = threadIdx.x;
  float s = 0.f;
  for (int k = t; k < KK; k += 256) {
    float p = (float)hist[k] * (1.f / 16384.f);
    s += p * logf(p + 1e-10f);
  }
  sred[t] = s;
  __syncthreads();
  for (int off = 128; off > 0; off >>= 1) {
    if (t < off) sred[t] += sred[t + off];
    __syncthreads();
  }
  if (t == 0) {
    float L = loss[0] / (float)NELEM;
    out[NELEM] = 1.25f * L;
    out[(size_t)NELEM + 1 + NROWS] = expf(-sred[0]);
  }
}

extern "C" void kernel_launch(void* const* d_in, const int* in_sizes, int n_in,
                              void* d_out, int out_size, void* d_ws, size_t ws_size,
                              hipStream_t stream) {
  const float* z = (const float*)d_in[0];   // (16,256,32,32) fp32
  const float* cb = (const float*)d_in[1];  // (8192,256) fp32
  float* out = (float*)d_out;               // fp32: [z_q_st | loss | idx | perp]

  float* wsf = (float*)d_ws;
  int* hist = (int*)d_ws;                          // 8192 ints
  float* loss = wsf + 8192;                        // 1 (+pad)
  float* Bk = wsf + 8448;                          // 8192
  float* Arow = wsf + 16640;                       // 16384
  u64* rowBest = (u64*)(wsf + 33024);              // 16384 u64 (128 KB)
  ushort* cbB = (ushort*)(wsf + 65792);            // 2.10M ushorts (4.2 MB)
  ushort* zB = (ushort*)(wsf + 1114368);           // 4.19M ushorts (8.4 MB)
  float* tA = wsf + 3211520;                       // 256*16384 f32 (16.8 MB)
  uint* tB = (uint*)(wsf + 7405824);               // 256*16384 u32 (16.8 MB)

  hipMemsetAsync(d_ws, 0, 8448 * sizeof(float), stream);
  hipMemsetAsync(rowBest, 0xFF, NROWS * sizeof(u64), stream);
  vq_prep<<<1184, 256, 0, stream>>>(z, cb, Bk, Arow, cbB, zB);
  vq_screen<<<(NROWS / MT) * 2, 256, 0, stream>>>(zB, cbB, Bk, tA, tB);
  vq_rerank<<<NROWS / MT, 256, 0, stream>>>(z, cb, Bk, Arow, tA, tB, out,
                                            hist, loss, rowBest);
  vq_final<<<1, 256, 0, stream>>>(hist, loss, out);
}

// Round 3
// 238.402 us; speedup vs baseline: 1.8457x; 1.0175x over previous
//
#include <hip/hip_runtime.h>

#define DD 256
#define KK 8192
#define HW 1024
#define NROWS 16384
#define NELEM 4194304
#define MT 32
#define MARGIN 6e-4f
#define WCAP 512
#define NT 256          // 8192 codes / 32-code tiles
#define NSLICE 4        // bid = rt*4+cs -> XCD x serves only cs = x&3

typedef __attribute__((ext_vector_type(8))) short short8;
typedef __attribute__((ext_vector_type(4))) float f32x4;
typedef unsigned short ushort;
typedef unsigned int uint;
typedef unsigned long long u64;

// ---- exact replication of numpy pairwise_sum (n=256) over squares ----
__device__ __forceinline__ float np_pw128_sq(const float* p) {
  float r[8];
#pragma unroll
  for (int j = 0; j < 8; ++j) r[j] = __fmul_rn(p[j], p[j]);
  for (int i = 8; i < 128; i += 8) {
#pragma unroll
    for (int j = 0; j < 8; ++j)
      r[j] = __fadd_rn(r[j], __fmul_rn(p[i + j], p[i + j]));
  }
  return __fadd_rn(__fadd_rn(__fadd_rn(r[0], r[1]), __fadd_rn(r[2], r[3])),
                   __fadd_rn(__fadd_rn(r[4], r[5]), __fadd_rn(r[6], r[7])));
}

__device__ __forceinline__ ushort f2bf(float x) {   // RNE float->bf16 bits
  uint u = __float_as_uint(x);
  u += 0x7FFF + ((u >> 16) & 1);
  return (ushort)(u >> 16);
}

// running top-2 (min, argmin, min2) helpers for the screen
struct Top2 { float m1, m2; int i1; };

__device__ __forceinline__ void top2_upd(Top2& s, const f32x4 a,
                                         const f32x4 Bs, int ibase) {
  float d0 = fmaf(-2.f, a[0], Bs[0]);
  float d1 = fmaf(-2.f, a[1], Bs[1]);
  float d2 = fmaf(-2.f, a[2], Bs[2]);
  float d3 = fmaf(-2.f, a[3], Bs[3]);
  float lo01 = fminf(d0, d1), hi01 = fmaxf(d0, d1);
  int io01 = d1 < d0 ? ibase + 1 : ibase;
  float lo23 = fminf(d2, d3), hi23 = fmaxf(d2, d3);
  int io23 = d3 < d2 ? ibase + 3 : ibase + 2;
  float n1 = fminf(lo01, lo23);
  int ni = lo23 < lo01 ? io23 : io01;
  float n2 = fminf(fmaxf(lo01, lo23), fminf(hi01, hi23));
  s.m2 = fminf(fmaxf(s.m1, n1), fminf(s.m2, n2));   // uses OLD m1
  s.i1 = n1 < s.m1 ? ni : s.i1;
  s.m1 = fminf(s.m1, n1);
}

__device__ __forceinline__ void top2_bfly(Top2& s, int off) {
  float om1 = __shfl_xor(s.m1, off);
  int oi1 = __shfl_xor(s.i1, off);
  float om2 = __shfl_xor(s.m2, off);
  s.m2 = fminf(fmaxf(s.m1, om1), fminf(s.m2, om2));
  s.i1 = om1 < s.m1 ? oi1 : s.i1;   // ties keep own; covered by m2<=thr path
  s.m1 = fminf(s.m1, om1);
}

__device__ __forceinline__ uint pack_m2(float m2, int i1) {
  // bf16 rounded toward -inf (conservative: never hides a full-scan), idx in low bits
  uint u = __float_as_uint(m2);
  uint hi = u & 0xFFFF0000u;
  if ((u & 0x80000000u) && (u & 0xFFFFu)) hi += 0x10000u;
  return hi | (uint)i1;
}

// ======== prep: Bk | cbB fragments (z-derived passes all removed) ========
__global__ __launch_bounds__(256) void vq_prep(const float* __restrict__ cb,
                                               float* __restrict__ Bk,
                                               ushort* __restrict__ cbB) {
  const int b = blockIdx.x, t = threadIdx.x;
  if (b < 32) {                // ||e_k||^2, numpy-exact
    int k = b * 256 + t;
    const float* p = cb + (size_t)k * DD;
    Bk[k] = __fadd_rn(np_pw128_sq(p), np_pw128_sq(p + 128));
  } else {                     // cbB fragments (layout verified r7/r8/r9)
    int tid = (b - 32) * 256 + t;
    int g = tid >> 9, s = (tid >> 6) & 7, lane = tid & 63;
    int code = g * 16 + (lane & 15);
    int dbase = s * 32 + (lane >> 4) * 8;
    const float* p = cb + (size_t)code * DD + dbase;
    ushort bb[8];
#pragma unroll
    for (int j = 0; j < 8; ++j) bb[j] = f2bf(p[j]);
    uint4 pk;
    pk.x = bb[0] | ((uint)bb[1] << 16);
    pk.y = bb[2] | ((uint)bb[3] << 16);
    pk.z = bb[4] | ((uint)bb[5] << 16);
    pk.w = bb[6] | ((uint)bb[7] << 16);
    *(uint4*)(cbB + (size_t)tid * 8) = pk;
  }
}

// ======== screen: swapped-operand MFMA, per-tile32 (min, argmin, min2) ======
// z fragments built in-kernel: stage tile as bf16 in LDS (f2bf at stage time
// == f2bf at extract time -> bit-identical fragments to the zB path), extract
// aF once. Inner loop byte-identical logic to the verified round-2 screen.
__global__ __launch_bounds__(256) void vq_screen(
    const float* __restrict__ z, const ushort* __restrict__ cbB,
    const float* __restrict__ Bk, float* __restrict__ tA,
    uint* __restrict__ tB) {
  __shared__ ushort ztB[MT][264];   // 264 = 256 + 16B pad (alignment-safe)
  const int bid = blockIdx.x;
  const int rt = bid >> 2, cs = bid & 3;
  const int t = threadIdx.x;
  const int n0 = rt * MT;
  const int bimg = n0 >> 10, hw0 = n0 & 1023;
  const float* zb = z + (size_t)bimg * DD * HW + hw0;

  for (int li = t; li < MT * 128; li += 256) {   // 32 rows x 128 d-pairs
    int r = li & 31, dp = li >> 5;
    float v0 = zb[(size_t)(2 * dp) * HW + r];
    float v1 = zb[(size_t)(2 * dp + 1) * HW + r];
    *(uint*)&ztB[r][2 * dp] = (uint)f2bf(v0) | ((uint)f2bf(v1) << 16);
  }
  __syncthreads();

  const int w = t >> 6, lane = t & 63;
  const int quad = lane >> 4, n16 = lane & 15;

  short8 aF[2][8];            // z fragments (B operand), m89-verified layout
#pragma unroll
  for (int rg = 0; rg < 2; ++rg)
#pragma unroll
    for (int s = 0; s < 8; ++s)
      aF[rg][s] = *(const short8*)&ztB[rg * 16 + n16][s * 32 + quad * 8];

  const int gg0 = cs * 128 + w * 32;   // 32 16-code groups = 16 tiles per wave
  Top2 c0 = {3.4e38f, 3.4e38f, 0}, c1 = {3.4e38f, 3.4e38f, 0};

  short8 b0[8], b1[8];
  {
    const ushort* bp = cbB + (size_t)gg0 * 4096 + lane * 8;
#pragma unroll
    for (int s = 0; s < 8; ++s) b0[s] = *(const short8*)(bp + s * 512);
  }

  for (int gp = 0; gp < 16; ++gp) {     // ping-pong pairs; tile = gg pair
    const int gg = gg0 + gp * 2;
    {
      const ushort* bp = cbB + (size_t)(gg + 1) * 4096 + lane * 8;
#pragma unroll
      for (int s = 0; s < 8; ++s) b1[s] = *(const short8*)(bp + s * 512);
    }
    {   // even gg
      f32x4 a0 = {0.f, 0.f, 0.f, 0.f}, a1 = {0.f, 0.f, 0.f, 0.f};
#pragma unroll
      for (int s = 0; s < 8; ++s) {
        a0 = __builtin_amdgcn_mfma_f32_16x16x32_bf16(b0[s], aF[0][s], a0, 0, 0, 0);
        a1 = __builtin_amdgcn_mfma_f32_16x16x32_bf16(b0[s], aF[1][s], a1, 0, 0, 0);
      }
      const f32x4 Bs = *(const f32x4*)(Bk + gg * 16 + quad * 4);
      top2_upd(c0, a0, Bs, quad * 4);
      top2_upd(c1, a1, Bs, quad * 4);
    }
    if (gp < 15) {
      const ushort* bp = cbB + (size_t)(gg + 2) * 4096 + lane * 8;
#pragma unroll
      for (int s = 0; s < 8; ++s) b0[s] = *(const short8*)(bp + s * 512);
    }
    {   // odd gg
      f32x4 a0 = {0.f, 0.f, 0.f, 0.f}, a1 = {0.f, 0.f, 0.f, 0.f};
#pragma unroll
      for (int s = 0; s < 8; ++s) {
        a0 = __builtin_amdgcn_mfma_f32_16x16x32_bf16(b1[s], aF[0][s], a0, 0, 0, 0);
        a1 = __builtin_amdgcn_mfma_f32_16x16x32_bf16(b1[s], aF[1][s], a1, 0, 0, 0);
      }
      const f32x4 Bs = *(const f32x4*)(Bk + (gg + 1) * 16 + quad * 4);
      top2_upd(c0, a0, Bs, 16 + quad * 4);
      top2_upd(c1, a1, Bs, 16 + quad * 4);
    }
    // tile complete: merge quads, store, reset
    top2_bfly(c0, 16); top2_bfly(c0, 32);
    top2_bfly(c1, 16); top2_bfly(c1, 32);
    const size_t tbase = (size_t)(gg >> 1) * NROWS + n0;
    if (quad == 0) {
      tA[tbase + n16] = c0.m1;
      tB[tbase + n16] = pack_m2(c0.m2, c0.i1);
    } else if (quad == 1) {
      tA[tbase + 16 + n16] = c1.m1;
      tB[tbase + 16 + n16] = pack_m2(c1.m2, c1.i1);
    }
    c0.m1 = 3.4e38f; c0.m2 = 3.4e38f; c0.i1 = 0;
    c1.m1 = 3.4e38f; c1.m2 = 3.4e38f; c1.i1 = 0;
  }
}

// ======== rerank: per-code candidates | exact chains | epilogue ========
// Arow now computed in-kernel from the staged zt (same f32 values, same
// np-exact op order as the old prep pass -> bit-identical).
__global__ __launch_bounds__(256) void vq_rerank(
    const float* __restrict__ z, const float* __restrict__ cb,
    const float* __restrict__ Bk, const float* __restrict__ tA,
    const uint* __restrict__ tB, float* __restrict__ out,
    int* __restrict__ hist, float* __restrict__ loss_acc,
    u64* __restrict__ rowBest) {
  __shared__ float zt[MT][DD + 1];
  __shared__ float thr[MT];
  __shared__ float ArS[MT];
  __shared__ float partial[4][MT];
  __shared__ int wl[WCAP];
  __shared__ int wcnt;
  __shared__ int kwin[MT];
  __shared__ float lred[4];

  const int t = threadIdx.x;
  const int n0 = blockIdx.x * MT;
  const int bimg = n0 >> 10, hw0 = n0 & 1023;
  const float* zb = z + (size_t)bimg * DD * HW + hw0;

  if (t == 0) wcnt = 0;
  for (int li = t; li < MT * DD; li += 256) {
    int d = li >> 5, r = li & 31;
    zt[r][d] = zb[d * HW + r];
  }

  const int w = t >> 6, lane = t & 63;
  const int r = t & 31, j = t >> 5;   // 8 tile-stripes x 32 rows

  // per-row min over 256 tiles ([tile][row] layout: 128B-coalesced)
  float mn = 3.4e38f;
#pragma unroll 4
  for (int k = 0; k < 32; ++k)
    mn = fminf(mn, tA[(size_t)(j * 32 + k) * NROWS + n0 + r]);
  mn = fminf(mn, __shfl_xor(mn, 32));
  if (lane < 32) partial[w][r] = mn;
  __syncthreads();   // zt + partial ready
  if (t < MT) {
    thr[t] = fminf(fminf(partial[0][t], partial[1][t]),
                   fminf(partial[2][t], partial[3][t])) + MARGIN;
  } else if (t >= 128 && t < 192) {   // wave 2: Arow from zt, numpy-exact
    int rr = (t - 128) >> 1, half = t & 1;
    float h = np_pw128_sq(&zt[rr][half * 128]);
    float ho = __shfl_xor(h, 1);      // partner half (adjacent lane)
    if (half == 0) ArS[rr] = __fadd_rn(h, ho);   // h[0] + h[1], order kept
  }
  __syncthreads();

  auto exact_one = [&](int rr, int code) {   // numpy-exact ascending-d chain
    const float* cp = cb + (size_t)code * DD;
    float dot = 0.f;
#pragma unroll
    for (int d0 = 0; d0 < DD; d0 += 4) {
      float4 v = *(const float4*)(cp + d0);
      dot = fmaf(zt[rr][d0 + 0], v.x, dot);
      dot = fmaf(zt[rr][d0 + 1], v.y, dot);
      dot = fmaf(zt[rr][d0 + 2], v.z, dot);
      dot = fmaf(zt[rr][d0 + 3], v.w, dot);
    }
    float bd = __fsub_rn(__fadd_rn(ArS[rr], Bk[code]), __fmul_rn(2.f, dot));
    atomicMin(&rowBest[n0 + rr],
              ((u64)__float_as_uint(bd) << 32) | (unsigned)code);
  };

  // candidate scan: tile argmin if min<=thr<min2; full 32 codes if min2<=thr
  const float th = thr[r];
  for (int k = 0; k < 32; ++k) {
    const int tile = j * 32 + k;
    const float a = tA[(size_t)tile * NROWS + n0 + r];
    if (a <= th) {
      const uint pk = tB[(size_t)tile * NROWS + n0 + r];
      const float m2f = __uint_as_float(pk & 0xFFFF0000u);
      if (m2f <= th) {               // rare: in-tile near-tie -> full tile
        for (int c = 0; c < 32; ++c) {
          int pos = atomicAdd(&wcnt, 1);
          if (pos < WCAP) wl[pos] = (r << 16) | (tile * 32 + c);
          else exact_one(r, tile * 32 + c);
        }
      } else {
        int pos = atomicAdd(&wcnt, 1);
        if (pos < WCAP) wl[pos] = (r << 16) | (tile * 32 + (int)(pk & 31u));
        else exact_one(r, tile * 32 + (int)(pk & 31u));
      }
    }
  }
  __syncthreads();

  const int cnt = min(wcnt, WCAP);
  for (int e = t; e < cnt; e += 256) {
    const int ent = wl[e];
    exact_one(ent >> 16, ent & 0xFFFF);
  }
  __syncthreads();

  // ---- epilogue: indices + hist + z_q_st + loss (zt resident) ----
  if (t < MT) {
    u64 key = atomicMin(&rowBest[n0 + t], 0xFFFFFFFFFFFFFFFFull);  // read
    int bi = (int)(key & 0xFFFFFFFFull);
    kwin[t] = bi;
    atomicAdd(&hist[bi], 1);
    out[(size_t)NELEM + 1 + n0 + t] = (float)bi;
  }
  __syncthreads();

  float lsum = 0.f;
  for (int it = 0; it < MT * DD / 256; ++it) {
    int li = it * 256 + t;
    int d = li >> 5, rr = li & 31;
    float ze = zt[rr][d];
    float zq = cb[(size_t)kwin[rr] * DD + d];
    float diff = __fsub_rn(zq, ze);
    float st = __fadd_rn(ze, diff);        // z_e + (z_q - z_e)
    out[(size_t)(bimg * DD + d) * HW + hw0 + rr] = st;
    lsum = fmaf(diff, diff, lsum);
  }
#pragma unroll
  for (int off = 32; off > 0; off >>= 1) lsum += __shfl_down(lsum, off);
  if (lane == 0) lred[w] = lsum;
  __syncthreads();
  if (t == 0)
    atomicAdd(loss_acc, ((lred[0] + lred[1]) + (lred[2] + lred[3])));
}

// ---------------- finalize: vq_loss + perplexity ----------------
__global__ __launch_bounds__(256) void vq_final(const int* __restrict__ hist,
                                                const float* __restrict__ loss,
                                                float* __restrict__ out) {
  __shared__ float sred[256];
  int t = threadIdx.x;
  float s = 0.f;
  for (int k = t; k < KK; k += 256) {
    float p = (float)hist[k] * (1.f / 16384.f);
    s += p * logf(p + 1e-10f);
  }
  sred[t] = s;
  __syncthreads();
  for (int off = 128; off > 0; off >>= 1) {
    if (t < off) sred[t] += sred[t + off];
    __syncthreads();
  }
  if (t == 0) {
    float L = loss[0] / (float)NELEM;
    out[NELEM] = 1.25f * L;
    out[(size_t)NELEM + 1 + NROWS] = expf(-sred[0]);
  }
}

extern "C" void kernel_launch(void* const* d_in, const int* in_sizes, int n_in,
                              void* d_out, int out_size, void* d_ws, size_t ws_size,
                              hipStream_t stream) {
  const float* z = (const float*)d_in[0];   // (16,256,32,32) fp32
  const float* cb = (const float*)d_in[1];  // (8192,256) fp32
  float* out = (float*)d_out;               // fp32: [z_q_st | loss | idx | perp]

  float* wsf = (float*)d_ws;
  int* hist = (int*)d_ws;                          // 8192 ints
  float* loss = wsf + 8192;                        // 1 (+pad)
  float* Bk = wsf + 8448;                          // 8192
  u64* rowBest = (u64*)(wsf + 16640);              // 16384 u64 (128 KB)
  ushort* cbB = (ushort*)(wsf + 49408);            // 2.10M ushorts (4.2 MB)
  float* tA = wsf + 1097984;                       // 256*16384 f32 (16.8 MB)
  uint* tB = (uint*)(wsf + 5292288);               // 256*16384 u32 (16.8 MB)

  hipMemsetAsync(d_ws, 0, 8448 * sizeof(float), stream);
  hipMemsetAsync(rowBest, 0xFF, NROWS * sizeof(u64), stream);
  vq_prep<<<1056, 256, 0, stream>>>(cb, Bk, cbB);
  vq_screen<<<(NROWS / MT) * NSLICE, 256, 0, stream>>>(z, cbB, Bk, tA, tB);
  vq_rerank<<<NROWS / MT, 256, 0, stream>>>(z, cb, Bk, tA, tB, out,
                                            hist, loss, rowBest);
  vq_final<<<1, 256, 0, stream>>>(hist, loss, out);
}